// Round 1
// baseline (5584.254 us; speedup 1.0000x reference)
//
#include <hip/hip_runtime.h>

// ---------------- constants ----------------
constexpr int LAYERS = 8;
constexpr int DIM    = 1024;
constexpr int NH     = 16;
constexpr int DK     = 64;
constexpr int FF     = 4096;
constexpr int VOC    = 32000;
constexpr int SEQ    = 1024;
constexpr int BATCH  = 2;
constexpr int MR     = BATCH * SEQ;   // 2048 rows

using bf16x8 = __attribute__((ext_vector_type(8))) short;
using f32x4  = __attribute__((ext_vector_type(4))) float;

static __device__ __forceinline__ short f2bf(float f) {
  unsigned u = __builtin_bit_cast(unsigned, f);
  u += 0x7fffu + ((u >> 16) & 1u);   // round-to-nearest-even
  return (short)(u >> 16);
}

// ---------------- embedding ----------------
__global__ __launch_bounds__(256) void embed_kernel(
    const int* __restrict__ ids, const float* __restrict__ tok,
    const float* __restrict__ pos, float* __restrict__ x) {
  int row = blockIdx.x;               // b*SEQ + s
  int s   = row & (SEQ - 1);
  int id  = ids[row];
  int c   = threadIdx.x;              // 256 threads x float4 = 1024
  const float4* t4 = (const float4*)(tok + (size_t)id * DIM);
  const float4* p4 = (const float4*)(pos + (size_t)s * DIM);
  float4* x4 = (float4*)(x + (size_t)row * DIM);
  float4 tv = t4[c], pv = p4[c];
  x4[c] = make_float4(tv.x + pv.x, tv.y + pv.y, tv.z + pv.z, tv.w + pv.w);
}

// ---------------- layernorm (fp32 in, bf16 out) ----------------
__global__ __launch_bounds__(256) void ln_kernel(
    const float* __restrict__ x, const float* __restrict__ g,
    const float* __restrict__ b, short* __restrict__ out) {
  int row = blockIdx.x;
  int tid = threadIdx.x;
  const float4* x4 = (const float4*)(x + (size_t)row * DIM);
  float4 v = x4[tid];
  float s = v.x + v.y + v.z + v.w;
  float q = v.x * v.x + v.y * v.y + v.z * v.z + v.w * v.w;
  __shared__ float rs[256], rq[256];
  rs[tid] = s; rq[tid] = q;
  __syncthreads();
  for (int off = 128; off; off >>= 1) {
    if (tid < off) { rs[tid] += rs[tid + off]; rq[tid] += rq[tid + off]; }
    __syncthreads();
  }
  float mean = rs[0] * (1.0f / DIM);
  float var  = rq[0] * (1.0f / DIM) - mean * mean;
  float inv  = rsqrtf(var + 1e-5f);
  float4 gv = ((const float4*)g)[tid];
  float4 bv = ((const float4*)b)[tid];
  int c = tid * 4;
  size_t base = (size_t)row * DIM + c;
  out[base + 0] = f2bf((v.x - mean) * inv * gv.x + bv.x);
  out[base + 1] = f2bf((v.y - mean) * inv * gv.y + bv.y);
  out[base + 2] = f2bf((v.z - mean) * inv * gv.z + bv.z);
  out[base + 3] = f2bf((v.w - mean) * inv * gv.w + bv.w);
}

// ---------------- MFMA GEMM: C = A(bf16) @ B(f32->bf16) + bias [+resid] [relu] ----------------
// A: [M,K] bf16 row-major.  B: [K,N] f32 row-major.  Block tile 128x128, BK=32.
// 4 waves in 2x2, each wave 64x64 = 4x4 tiles of 16x16x32 MFMA.
template<int OUT_BF16, int RELU, int RESID>
static __device__ __forceinline__ void gemm_body(
    const short* __restrict__ A, const float* __restrict__ Bw,
    const float* __restrict__ bias, const float* resid,
    float* Cf, short* Cb, int Nsz, int Ksz) {
  constexpr int BM = 128, BN = 128, BK = 32, LDK = 40;  // LDK pad: 80B rows
  __shared__ __align__(16) short As[BM * LDK];
  __shared__ __align__(16) short Bs[BN * LDK];
  int tid  = threadIdx.x;
  int lane = tid & 63, wave = tid >> 6;
  int quad = lane >> 4, l16 = lane & 15;
  int wm = wave >> 1, wn = wave & 1;
  int mBase = blockIdx.x * BM, nBase = blockIdx.y * BN;
  f32x4 acc[4][4] = {};
  for (int k0 = 0; k0 < Ksz; k0 += BK) {
    __syncthreads();
    // stage A tile: 128 rows x 32 k (bf16), 16B per thread-load, 2 passes
    #pragma unroll
    for (int p = 0; p < 2; ++p) {
      int i = p * 256 + tid;            // 0..511
      int row = i >> 2, kc = (i & 3) * 8;
      *(int4*)(As + row * LDK + kc) =
          *(const int4*)(A + (size_t)(mBase + row) * Ksz + k0 + kc);
    }
    // stage B tile transposed: Bs[n][k], convert f32->bf16
    #pragma unroll
    for (int p = 0; p < 4; ++p) {
      int i = p * 256 + tid;            // 0..1023
      int kk = i >> 5, n4 = (i & 31) * 4;
      float4 w = *(const float4*)(Bw + (size_t)(k0 + kk) * Nsz + nBase + n4);
      Bs[(n4 + 0) * LDK + kk] = f2bf(w.x);
      Bs[(n4 + 1) * LDK + kk] = f2bf(w.y);
      Bs[(n4 + 2) * LDK + kk] = f2bf(w.z);
      Bs[(n4 + 3) * LDK + kk] = f2bf(w.w);
    }
    __syncthreads();
    bf16x8 af[4];
    #pragma unroll
    for (int ti = 0; ti < 4; ++ti)
      af[ti] = *(const bf16x8*)(As + (wm * 64 + ti * 16 + l16) * LDK + quad * 8);
    #pragma unroll
    for (int tj = 0; tj < 4; ++tj) {
      bf16x8 bfr = *(const bf16x8*)(Bs + (wn * 64 + tj * 16 + l16) * LDK + quad * 8);
      #pragma unroll
      for (int ti = 0; ti < 4; ++ti)
        acc[ti][tj] = __builtin_amdgcn_mfma_f32_16x16x32_bf16(af[ti], bfr, acc[ti][tj], 0, 0, 0);
    }
  }
  // epilogue
  #pragma unroll
  for (int tj = 0; tj < 4; ++tj) {
    int col = nBase + wn * 64 + tj * 16 + l16;
    float bv = bias[col];
    #pragma unroll
    for (int ti = 0; ti < 4; ++ti) {
      #pragma unroll
      for (int r = 0; r < 4; ++r) {
        int row = mBase + wm * 64 + ti * 16 + quad * 4 + r;
        float val = acc[ti][tj][r] + bv;
        if (RESID) val += resid[(size_t)row * Nsz + col];
        if (RELU)  val = fmaxf(val, 0.0f);
        if (OUT_BF16) Cb[(size_t)row * Nsz + col] = f2bf(val);
        else          Cf[(size_t)row * Nsz + col] = val;
      }
    }
  }
}

template<int OUT_BF16, int RELU, int RESID>
__global__ __launch_bounds__(256) void gemm_kernel(
    const short* A, const float* Bw, const float* bias, const float* resid,
    float* Cf, short* Cb, int Nsz, int Ksz) {
  gemm_body<OUT_BF16, RELU, RESID>(A, Bw, bias, resid, Cf, Cb, Nsz, Ksz);
}

__global__ __launch_bounds__(256) void gemm_qkv_kernel(
    const short* A, const float* W0, const float* W1, const float* W2,
    const float* b0, const float* b1, const float* b2,
    float* o0, float* o1, float* o2, int Nsz, int Ksz) {
  int z = blockIdx.z;
  const float* Bw   = (z == 0) ? W0 : (z == 1) ? W1 : W2;
  const float* bias = (z == 0) ? b0 : (z == 1) ? b1 : b2;
  float* Cf         = (z == 0) ? o0 : (z == 1) ? o1 : o2;
  gemm_body<0, 0, 0>(A, Bw, bias, nullptr, Cf, nullptr, Nsz, Ksz);
}

// ---------------- flash attention (bf16 MFMA, online softmax) ----------------
// grid: (SEQ/16, NH, BATCH), block: 64 (1 wave). One wave handles 16 queries.
__global__ __launch_bounds__(64) void attn_kernel(
    const float* __restrict__ q, const float* __restrict__ k,
    const float* __restrict__ v, short* __restrict__ out) {
  int qt = blockIdx.x, h = blockIdx.y, b = blockIdx.z;
  int lane = threadIdx.x;
  int quad = lane >> 4, l16 = lane & 15;
  int qbase = qt * 16;
  const size_t baseRow = (size_t)b * SEQ;
  const float scale = 0.125f;  // 1/sqrt(64)

  // Q fragments: A-layout, lane holds Q[m=l16][d=c*32+quad*8+j]
  bf16x8 qf[2];
  {
    int qrow = qbase + l16;
    const float* qp = q + (baseRow + qrow) * DIM + h * DK;
    #pragma unroll
    for (int c = 0; c < 2; ++c) {
      bf16x8 t;
      #pragma unroll
      for (int j = 0; j < 8; ++j) t[j] = f2bf(qp[c * 32 + quad * 8 + j]);
      qf[c] = t;
    }
  }

  f32x4 o_acc[4] = {};
  float Mr[4], Lr[4];
  #pragma unroll
  for (int r = 0; r < 4; ++r) { Mr[r] = -1e30f; Lr[r] = 0.0f; }
  __shared__ __align__(16) short Ps[16 * 32];

  int nkt = qbase / 32 + 1;  // causal: key tiles of 32 covering keys <= qbase+15
  for (int kt = 0; kt < nkt; ++kt) {
    // --- scores: two 16x16 tiles (t=0,1), K-dim = 64 via 2 mfma each ---
    f32x4 sc[2];
    #pragma unroll
    for (int t = 0; t < 2; ++t) {
      int krow = kt * 32 + t * 16 + l16;
      const float* kp = k + (baseRow + krow) * DIM + h * DK;
      f32x4 s = {};
      #pragma unroll
      for (int c = 0; c < 2; ++c) {
        bf16x8 kf;
        #pragma unroll
        for (int j = 0; j < 8; ++j) kf[j] = f2bf(kp[c * 32 + quad * 8 + j]);
        s = __builtin_amdgcn_mfma_f32_16x16x32_bf16(qf[c], kf, s, 0, 0, 0);
      }
      int kcol = kt * 32 + t * 16 + l16;
      #pragma unroll
      for (int r = 0; r < 4; ++r) {
        int qrow = qbase + quad * 4 + r;
        sc[t][r] = (kcol > qrow) ? -1e9f : s[r] * scale;
      }
    }
    // --- online softmax (rows quad*4+r, reduce over 16-lane col groups) ---
    float tm[4], alpha[4], p[2][4], rowsum[4];
    #pragma unroll
    for (int r = 0; r < 4; ++r) tm[r] = fmaxf(sc[0][r], sc[1][r]);
    #pragma unroll
    for (int off = 1; off < 16; off <<= 1) {
      #pragma unroll
      for (int r = 0; r < 4; ++r) tm[r] = fmaxf(tm[r], __shfl_xor(tm[r], off, 64));
    }
    #pragma unroll
    for (int r = 0; r < 4; ++r) {
      float mnew = fmaxf(Mr[r], tm[r]);
      alpha[r] = __expf(Mr[r] - mnew);
      Mr[r] = mnew;
      float p0 = __expf(sc[0][r] - mnew);
      float p1 = __expf(sc[1][r] - mnew);
      p[0][r] = p0; p[1][r] = p1;
      rowsum[r] = p0 + p1;
    }
    #pragma unroll
    for (int off = 1; off < 16; off <<= 1) {
      #pragma unroll
      for (int r = 0; r < 4; ++r) rowsum[r] += __shfl_xor(rowsum[r], off, 64);
    }
    #pragma unroll
    for (int r = 0; r < 4; ++r) Lr[r] = Lr[r] * alpha[r] + rowsum[r];
    #pragma unroll
    for (int n = 0; n < 4; ++n) {
      f32x4 t = o_acc[n];
      #pragma unroll
      for (int r = 0; r < 4; ++r) t[r] *= alpha[r];
      o_acc[n] = t;
    }
    // --- P: C-layout -> A-layout via LDS ---
    __syncthreads();
    #pragma unroll
    for (int t = 0; t < 2; ++t)
      #pragma unroll
      for (int r = 0; r < 4; ++r)
        Ps[(quad * 4 + r) * 32 + t * 16 + l16] = f2bf(p[t][r]);
    __syncthreads();
    bf16x8 pf = *(const bf16x8*)(Ps + l16 * 32 + quad * 8);
    // --- PV: B-frag = V[key=quad*8+j][d=n*16+l16] ---
    #pragma unroll
    for (int n = 0; n < 4; ++n) {
      bf16x8 vf;
      #pragma unroll
      for (int j = 0; j < 8; ++j) {
        int vrow = kt * 32 + quad * 8 + j;
        vf[j] = f2bf(v[(baseRow + vrow) * DIM + h * DK + n * 16 + l16]);
      }
      o_acc[n] = __builtin_amdgcn_mfma_f32_16x16x32_bf16(pf, vf, o_acc[n], 0, 0, 0);
    }
  }
  // --- write (bf16 for Wo GEMM A-operand) ---
  #pragma unroll
  for (int n = 0; n < 4; ++n) {
    #pragma unroll
    for (int r = 0; r < 4; ++r) {
      int qrow = qbase + quad * 4 + r;
      out[(baseRow + qrow) * DIM + h * DK + n * 16 + l16] = f2bf(o_acc[n][r] / Lr[r]);
    }
  }
}

// ---------------- launch ----------------
extern "C" void kernel_launch(void* const* d_in, const int* in_sizes, int n_in,
                              void* d_out, int out_size, void* d_ws, size_t ws_size,
                              hipStream_t stream) {
  (void)in_sizes; (void)n_in; (void)out_size; (void)ws_size;
  const int*   ids  = (const int*)d_in[0];
  const float* tok  = (const float*)d_in[1];
  const float* pos  = (const float*)d_in[2];
  const float* Wq   = (const float*)d_in[3];
  const float* bq   = (const float*)d_in[4];
  const float* Wk   = (const float*)d_in[5];
  const float* bk   = (const float*)d_in[6];
  const float* Wv   = (const float*)d_in[7];
  const float* bv   = (const float*)d_in[8];
  const float* Wo   = (const float*)d_in[9];
  const float* bo   = (const float*)d_in[10];
  const float* W1   = (const float*)d_in[11];
  const float* b1   = (const float*)d_in[12];
  const float* W2   = (const float*)d_in[13];
  const float* b2   = (const float*)d_in[14];
  const float* g1   = (const float*)d_in[15];
  const float* be1  = (const float*)d_in[16];
  const float* g2   = (const float*)d_in[17];
  const float* be2  = (const float*)d_in[18];
  const float* gf   = (const float*)d_in[19];
  const float* bfl  = (const float*)d_in[20];
  const float* Wout = (const float*)d_in[21];
  const float* bout = (const float*)d_in[22];
  float* outp = (float*)d_out;

  char* p = (char*)d_ws;
  float* x   = (float*)p;  p += (size_t)MR * DIM * 4;   // residual stream
  short* hb  = (short*)p;  p += (size_t)MR * DIM * 2;   // LN output bf16
  float* qb  = (float*)p;  p += (size_t)MR * DIM * 4;
  float* kb  = (float*)p;  p += (size_t)MR * DIM * 4;
  float* vb  = (float*)p;  p += (size_t)MR * DIM * 4;
  short* aob = (short*)p;  p += (size_t)MR * DIM * 2;   // attn out bf16
  short* ffb = (short*)p;  p += (size_t)MR * FF * 2;    // ffn1 out bf16

  embed_kernel<<<MR, 256, 0, stream>>>(ids, tok, pos, x);

  for (int l = 0; l < LAYERS; ++l) {
    ln_kernel<<<MR, 256, 0, stream>>>(x, g1 + l * DIM, be1 + l * DIM, hb);
    gemm_qkv_kernel<<<dim3(MR / 128, DIM / 128, 3), 256, 0, stream>>>(
        hb, Wq + (size_t)l * DIM * DIM, Wk + (size_t)l * DIM * DIM,
        Wv + (size_t)l * DIM * DIM, bq + l * DIM, bk + l * DIM, bv + l * DIM,
        qb, kb, vb, DIM, DIM);
    attn_kernel<<<dim3(SEQ / 16, NH, BATCH), 64, 0, stream>>>(qb, kb, vb, aob);
    gemm_kernel<0, 0, 1><<<dim3(MR / 128, DIM / 128), 256, 0, stream>>>(
        aob, Wo + (size_t)l * DIM * DIM, bo + l * DIM, x, x, nullptr, DIM, DIM);
    ln_kernel<<<MR, 256, 0, stream>>>(x, g2 + l * DIM, be2 + l * DIM, hb);
    gemm_kernel<1, 1, 0><<<dim3(MR / 128, FF / 128), 256, 0, stream>>>(
        hb, W1 + (size_t)l * DIM * FF, b1 + l * FF, nullptr, nullptr, ffb, FF, DIM);
    gemm_kernel<0, 0, 1><<<dim3(MR / 128, DIM / 128), 256, 0, stream>>>(
        ffb, W2 + (size_t)l * FF * DIM, b2 + l * DIM, x, x, nullptr, DIM, FF);
  }

  ln_kernel<<<MR, 256, 0, stream>>>(x, gf, bfl, hb);
  gemm_kernel<0, 0, 0><<<dim3(MR / 128, VOC / 128), 256, 0, stream>>>(
      hb, Wout, bout, nullptr, outp, nullptr, VOC, DIM);
}